// Round 16
// baseline (1026.267 us; speedup 1.0000x reference)
//
#include <hip/hip_runtime.h>
#include <stdint.h>

// Persistent-kernel RNN: 256 wgs (1/CU), GB=32 x GJ=8, register-resident W,
// direct-global A bursts (R15 structure, best verified 968us).
// R18 = R17 resubmission (R15 bench died with an INFRASTRUCTURE error:
// "UnresponsiveContainer ... connection closed" — no bench verdict). Only
// change: retry backoff s_sleep 8 -> 32 to cap the t=1 thundering-herd retry
// traffic (256 wgs x 8KB/wave re-bursts against the MALL).
// R17: TAG-IN-DATA exchange on the R15 structure — no flags, no drain.
//  Evidence R15==R16 (L2-cached A loads changed nothing, FETCH identical):
//  producers' sc0 sc1 stores write-INVALIDATE the XCD L2, so every h byte
//  crosses the MALL regardless; the step is ~4 serialized MALL RTTs
//  (store-drain, flag visible, poll detect, A-burst). Fewer hops is the only
//  lever left. Tag protocol (R9-proven correct on the old structure): each
//  16B h packet carries tag=(t>>1)&1 in the LSB of its first bf16. Consumer
//  A fragments ARE producer packets (both 16B at 8-col-aligned offsets), so
//  one LSB check per burst register validates freshness; t vs t-2 (ping-pong
//  stale) always differ in tag (tags 0,0,1,1,.. vs alternating parity).
//  Producer: store16, done. Consumer: optimistic burst -> TIED vmcnt wait ->
//  check 8 LSBs -> backoff retry (8KB/wave).
//  WAW safety: observing a peer's h(t-1) tag implies its h(t-2) loads retired
//  (tied-wait before MFMA, program-order before its store); all 8 producers
//  are collectively validated by the 4 waves before the pre-store reduction
//  barrier. Grounded at t=0 by per-launch hipMemsetAsync(0xFF) (LSB=1
//  mismatches expected tag 0 at t=1,2; also defeats reset()-zeroed workspace
//  whose zeros would alias tag 0). Retries terminate: sc0 sc1 loads can't
//  cache staleness; the pending store eventually lands at the MALL.
//  Numerics: LSB forced on 1/8 of h elements (<=1 ULP bf16) — R9 measured
//  0.0117 vs 0.0205 threshold on this exact scheme.
// Lessons kept: tied "+v" vmcnt waits + sched_barrier (R11 crash, R12 fix);
// sc0-only spin hangs (R3); buffer_inv sc1 = L2 nuke (R4); scope bits don't
// change exchange cost (R5==R6); retry needs backoff + small volume (R9).

#define BATCH 512
#define SEQ   256
#define HID   1024
#define CLS   128

#define GB 32          // batch groups
#define GJ 8           // hidden slices
#define BT 16          // batch rows per wg
#define JT 128         // hidden cols per wg
#define HSTR 132       // h exchange row stride (halves)
#define HS_OFF 16384   // halves: hS overlay at byte 32768 (above 32KB scratch)
#define SMEM_BYTES (32768 + BT * HSTR * 2)   // 36992 B
#define HBUF_HALVES (BATCH * HID)            // 1 MB per buffer

typedef __attribute__((ext_vector_type(8))) short  bf16x8;
typedef __attribute__((ext_vector_type(4))) short  s16x4;
typedef __attribute__((ext_vector_type(4))) float  f32x4;
typedef __attribute__((ext_vector_type(4))) int    i32x4;
typedef __attribute__((ext_vector_type(2))) unsigned int u32x2;

__device__ __forceinline__ unsigned short f2bf(float f) {
  unsigned int u = __float_as_uint(f);
  u = (u + 0x7FFFu + ((u >> 16) & 1u)) >> 16;   // RNE
  return (unsigned short)u;
}
__device__ __forceinline__ float b2f(short h) {
  return __uint_as_float(((unsigned int)(unsigned short)h) << 16);
}

// ---- device-coherent (MALL) accesses ----
__device__ __forceinline__ void store16(void* p, i32x4 v) {
  asm volatile("global_store_dwordx4 %0, %1, off sc0 sc1" :: "v"(p), "v"(v) : "memory");
}
__device__ __forceinline__ void waitcnt0() {
  asm volatile("s_waitcnt vmcnt(0)" ::: "memory");
}
// raw workgroup barrier: drains LDS ops only
__device__ __forceinline__ void barrier_lgkm() {
  asm volatile("s_waitcnt lgkmcnt(0)\n\ts_barrier" ::: "memory");
}
// 4x dwordx4 coherent loads, 64B apart (MFMA k-step stride)
__device__ __forceinline__ void issue4_64(const void* p, i32x4& a, i32x4& b, i32x4& c, i32x4& d) {
  asm volatile(
    "global_load_dwordx4 %0, %4, off sc0 sc1\n\t"
    "global_load_dwordx4 %1, %4, off offset:64 sc0 sc1\n\t"
    "global_load_dwordx4 %2, %4, off offset:128 sc0 sc1\n\t"
    "global_load_dwordx4 %3, %4, off offset:192 sc0 sc1"
    : "=&v"(a), "=&v"(b), "=&v"(c), "=&v"(d)
    : "v"(p) : "memory");
}
// 4x dwordx4 coherent loads, 16B apart (contiguous 64 B — head staging)
__device__ __forceinline__ void issue4_16(const void* p, i32x4& a, i32x4& b, i32x4& c, i32x4& d) {
  asm volatile(
    "global_load_dwordx4 %0, %4, off sc0 sc1\n\t"
    "global_load_dwordx4 %1, %4, off offset:16 sc0 sc1\n\t"
    "global_load_dwordx4 %2, %4, off offset:32 sc0 sc1\n\t"
    "global_load_dwordx4 %3, %4, off offset:48 sc0 sc1"
    : "=&v"(a), "=&v"(b), "=&v"(c), "=&v"(d)
    : "v"(p) : "memory");
}
// register-TIED vmcnt(0): binds all 8 burst regs so no consumer (tag check or
// MFMA) can be scheduled above the wait (rule #18 / R11 crash lesson).
#define TIED_WAIT8(A0,A1,A2,A3,A4,A5,A6,A7) \
  asm volatile("s_waitcnt vmcnt(0)" \
               : "+v"(A0), "+v"(A1), "+v"(A2), "+v"(A3), \
                 "+v"(A4), "+v"(A5), "+v"(A6), "+v"(A7) :: "memory")

__device__ __forceinline__ void wr16(short* p, i32x4 v) {  // 16 B to LDS as 2x b64
  u32x2 lo, hi;
  lo.x = (unsigned)v.x; lo.y = (unsigned)v.y;
  hi.x = (unsigned)v.z; hi.y = (unsigned)v.w;
  *(u32x2*)p = lo;
  *(u32x2*)(p + 4) = hi;
}
__device__ __forceinline__ float tanh_fast(float z) {
  float e = __expf(2.f * z);
  return 1.f - 2.f / (e + 1.f);
}
// stale if any packet's head-bf16 LSB != expected tag
__device__ __forceinline__ bool stale8(const i32x4& a, const i32x4& b,
                                       const i32x4& c, const i32x4& d,
                                       const i32x4& e, const i32x4& f,
                                       const i32x4& g, const i32x4& h, int tg) {
  return ((((a.x ^ tg) | (b.x ^ tg) | (c.x ^ tg) | (d.x ^ tg) |
            (e.x ^ tg) | (f.x ^ tg) | (g.x ^ tg) | (h.x ^ tg)) & 1)) != 0;
}

#define MFMA(a, b, c) __builtin_amdgcn_mfma_f32_16x16x32_bf16((a), (b), (c), 0, 0, 0)

__global__ void __launch_bounds__(256, 1)
rnn_persistent(const float* __restrict__ x, const float* __restrict__ Whx,
               const float* __restrict__ Whh, const float* __restrict__ bh,
               const float* __restrict__ Wph, const float* __restrict__ bp,
               float* __restrict__ out, unsigned short* hbuf)
{
  extern __shared__ short smem[];
  float* scr = (float*)smem;            // 32KB reduction scratch (head reuses)
  short* hS  = smem + HS_OFF;           // [BT][HSTR] exchange overlay

  const int tid  = threadIdx.x;
  const int bg   = blockIdx.x & 31;     // 32 batch groups
  const int jg   = blockIdx.x >> 5;     // 8 hidden slices
  const int lane = tid & 63;
  const int wv   = tid >> 6;            // wave = k-quarter owner
  const int l15  = lane & 15;
  const int quad = lane >> 4;

  // ---- W_hh into REGISTERS: cols jg*128+ct*16+l15, k = wv*256+ks*32+quad*8 ----
  bf16x8 barr[8][8];                    // 256 VGPR
#pragma unroll
  for (int ct = 0; ct < 8; ++ct) {
#pragma unroll
    for (int ks = 0; ks < 8; ++ks) {
      const float* wp = Whh + (jg * JT + ct * 16 + l15) * HID
                            + wv * 256 + ks * 32 + quad * 8;
      float4 fA = *(const float4*)(wp);
      float4 fB = *(const float4*)(wp + 4);
      union { bf16x8 v8; s16x4 h[2]; } u;
      u.h[0].x = (short)f2bf(fA.x); u.h[0].y = (short)f2bf(fA.y);
      u.h[0].z = (short)f2bf(fA.z); u.h[0].w = (short)f2bf(fA.w);
      u.h[1].x = (short)f2bf(fB.x); u.h[1].y = (short)f2bf(fB.y);
      u.h[1].z = (short)f2bf(fB.z); u.h[1].w = (short)f2bf(fB.w);
      barr[ct][ks] = u.v8;
    }
  }

  // this lane finishes col-tiles 2wv and 2wv+1 after the k-reduction
  const int j0 = jg * JT + wv * 32 + l15;
  const int j1 = j0 + 16;
  const float whx0 = Whx[j0], whx1 = Whx[j1];
  const float bhv0 = bh[j0],  bhv1 = bh[j1];
  const int tagger = (l15 & 7) == 0;      // this lane's cols are packet heads

  // exchange thread mapping: 16 rows x 16 segs x 16 B
  const int sr  = tid >> 4;               // 0..15 row
  const int seg = tid & 15;               // 0..15

  for (int t = 0; t < SEQ; ++t) {
    const unsigned short* hin = hbuf + ((t + 1) & 1) * HBUF_HALVES;
    unsigned short*      hout = hbuf + (t & 1) * HBUF_HALVES;
    const int tg_w = (t >> 1) & 1;
    const int tg_r = ((t - 1) >> 1) & 1;

    f32x4 acc0 = {0,0,0,0}, acc1 = {0,0,0,0}, acc2 = {0,0,0,0}, acc3 = {0,0,0,0};
    f32x4 acc4 = {0,0,0,0}, acc5 = {0,0,0,0}, acc6 = {0,0,0,0}, acc7 = {0,0,0,0};

    // x for this step: rows bg*16 + quad*4 + rg (plain loads, compiler-waited)
    float xv[4];
    {
      const float* xp = x + (bg * BT + quad * 4) * SEQ + t;
#pragma unroll
      for (int rg = 0; rg < 4; ++rg) xv[rg] = xp[rg * SEQ];
    }

    if (t > 0) {
      // OPTIMISTIC A burst — no spin, no flag. Each reg is one producer
      // packet; tags self-validate. Retry (rare) with backoff.
      const short* pA = (const short*)hin + (bg * BT + l15) * HID
                        + wv * 256 + quad * 8;
      i32x4 A0, A1, A2, A3, A4, A5, A6, A7;
      issue4_64(pA,       A0, A1, A2, A3);   // ks 0..3
      issue4_64(pA + 128, A4, A5, A6, A7);   // ks 4..7
      TIED_WAIT8(A0, A1, A2, A3, A4, A5, A6, A7);
      if (__builtin_expect(stale8(A0, A1, A2, A3, A4, A5, A6, A7, tg_r), 0)) {
        do {
          asm volatile("s_sleep 32" ::: "memory");
          issue4_64(pA,       A0, A1, A2, A3);
          issue4_64(pA + 128, A4, A5, A6, A7);
          TIED_WAIT8(A0, A1, A2, A3, A4, A5, A6, A7);
        } while (stale8(A0, A1, A2, A3, A4, A5, A6, A7, tg_r));
      }
      __builtin_amdgcn_sched_barrier(0);

#define KSTEP(Ar, KS) { \
      bf16x8 _a = *(const bf16x8*)&(Ar); \
      acc0 = MFMA(_a, barr[0][KS], acc0); acc1 = MFMA(_a, barr[1][KS], acc1); \
      acc2 = MFMA(_a, barr[2][KS], acc2); acc3 = MFMA(_a, barr[3][KS], acc3); \
      acc4 = MFMA(_a, barr[4][KS], acc4); acc5 = MFMA(_a, barr[5][KS], acc5); \
      acc6 = MFMA(_a, barr[6][KS], acc6); acc7 = MFMA(_a, barr[7][KS], acc7); }
      KSTEP(A0, 0) KSTEP(A1, 1) KSTEP(A2, 2) KSTEP(A3, 3)
      KSTEP(A4, 4) KSTEP(A5, 5) KSTEP(A6, 6) KSTEP(A7, 7)
#undef KSTEP
    }

    // ---- cross-wave k-reduction: scr[(ct*4 + wv)*64 + lane] (f32x4 slots) ----
    barrier_lgkm();   // prior-step scratch/hS readers done; joins waves
#pragma unroll
    for (int ct = 0; ct < 8; ++ct) {
      f32x4 w = (ct == 0) ? acc0 : (ct == 1) ? acc1 : (ct == 2) ? acc2 :
                (ct == 3) ? acc3 : (ct == 4) ? acc4 : (ct == 5) ? acc5 :
                (ct == 6) ? acc6 : acc7;
      *(f32x4*)(scr + ((ct * 4 + wv) * 64 + lane) * 4) = w;
    }
    barrier_lgkm();
    {
      f32x4 f0 = {0,0,0,0}, f1 = {0,0,0,0};
#pragma unroll
      for (int w = 0; w < 4; ++w) {
        f0 += *(const f32x4*)(scr + (((2 * wv)     * 4 + w) * 64 + lane) * 4);
        f1 += *(const f32x4*)(scr + (((2 * wv + 1) * 4 + w) * 64 + lane) * 4);
      }
      // h = tanh(acc + x*whx + bh) -> hS; packet-head lanes carry the tag
#pragma unroll
      for (int rg = 0; rg < 4; ++rg) {
        unsigned short v0 = f2bf(tanh_fast(f0[rg] + xv[rg] * whx0 + bhv0));
        unsigned short v1 = f2bf(tanh_fast(f1[rg] + xv[rg] * whx1 + bhv1));
        if (tagger) {
          v0 = (unsigned short)((v0 & 0xFFFEu) | (unsigned)tg_w);
          v1 = (unsigned short)((v1 & 0xFFFEu) | (unsigned)tg_w);
        }
        hS[(quad * 4 + rg) * HSTR + wv * 32 + l15]      = (short)v0;
        hS[(quad * 4 + rg) * HSTR + wv * 32 + 16 + l15] = (short)v1;
      }
    }
    barrier_lgkm();   // hS complete
    {
      const short* hsrc = hS + sr * HSTR + seg * 8;
      u32x2 lo = *(const u32x2*)(hsrc);
      u32x2 hi = *(const u32x2*)(hsrc + 4);
      i32x4 sv; sv.x = (int)lo.x; sv.y = (int)lo.y; sv.z = (int)hi.x; sv.w = (int)hi.y;
      unsigned short* dst = hout + (bg * BT + sr) * HID + jg * JT + seg * 8;
      store16(dst, sv);   // release: no drain, no flag — the tag IS the flag
    }
    // no trailing barrier: next step's first barrier_lgkm drains hS reads
  }

  // ---- output head: out[b, jg*16+cc] = h_last . W_ph[c] + b_p ----
  barrier_lgkm();   // last step's hS/scr readers done before smem reuse

  // stage h_last (16 x 1024 bf16 = 32KB) into smem: thread (sr, seg) owns the
  // CONTIGUOUS 128 B at row sr, bytes seg*128..+128; tag-validated (tg=1).
  const unsigned short* hlast = hbuf + ((SEQ - 1) & 1) * HBUF_HALVES;
  const int tg_l = ((SEQ - 1) >> 1) & 1;   // = 1
  {
    const char* lbase = (const char*)(hlast + (bg * BT + sr) * HID) + seg * 128;
    i32x4 p0, p1, p2, p3, p4, p5, p6, p7;
    issue4_16(lbase,      p0, p1, p2, p3);   // bytes 0,16,32,48
    issue4_16(lbase + 64, p4, p5, p6, p7);   // bytes 64,80,96,112
    TIED_WAIT8(p0, p1, p2, p3, p4, p5, p6, p7);
    if (stale8(p0, p1, p2, p3, p4, p5, p6, p7, tg_l)) {
      do {
        asm volatile("s_sleep 32" ::: "memory");
        issue4_16(lbase,      p0, p1, p2, p3);
        issue4_16(lbase + 64, p4, p5, p6, p7);
        TIED_WAIT8(p0, p1, p2, p3, p4, p5, p6, p7);
      } while (stale8(p0, p1, p2, p3, p4, p5, p6, p7, tg_l));
    }
    short* sdst = smem + sr * 1028 + seg * 64;   // [16][1028] halves
    wr16(sdst,      p0); wr16(sdst + 8,  p1); wr16(sdst + 16, p2); wr16(sdst + 24, p3);
    wr16(sdst + 32, p4); wr16(sdst + 40, p5); wr16(sdst + 48, p6); wr16(sdst + 56, p7);
  }
  __syncthreads();
  {
    const int hr = tid >> 4;            // 0..15 batch row
    const int cc = tid & 15;            // 0..15 class col within slice
    const int cg = jg * 16 + cc;
    const float* wp = Wph + cg * HID;
    const short* hs = smem + hr * 1028;
    float acc = 0.f;
#pragma unroll 8
    for (int k4 = 0; k4 < 256; ++k4) {
      float4 w  = *(const float4*)(wp + k4 * 4);
      s16x4 hv  = *(const s16x4*)(hs + k4 * 4);
      acc += b2f(hv.x) * w.x + b2f(hv.y) * w.y + b2f(hv.z) * w.z + b2f(hv.w) * w.w;
    }
    out[(bg * BT + hr) * CLS + cg] = acc + bp[cg];
  }
}

extern "C" void kernel_launch(void* const* d_in, const int* in_sizes, int n_in,
                              void* d_out, int out_size, void* d_ws, size_t ws_size,
                              hipStream_t stream) {
  const float* x   = (const float*)d_in[0];
  const float* Whx = (const float*)d_in[1];
  const float* Whh = (const float*)d_in[2];
  const float* bh  = (const float*)d_in[3];
  const float* Wph = (const float*)d_in[4];
  const float* bp  = (const float*)d_in[5];
  float* out = (float*)d_out;

  unsigned short* hbuf = (unsigned short*)d_ws;

  // Re-tag both ping-pong buffers each launch: 0xFF halves have LSB=1, which
  // mismatches the expected tag 0 at t=1,2 — covers first launch, graph
  // replay, reset()-zeroed workspace (zeros would ALIAS tag 0!), and stale
  // data from a previous run. Stream-ordered, capture-safe.
  hipMemsetAsync(d_ws, 0xFF, (size_t)2 * HBUF_HALVES * 2, stream);

  hipFuncSetAttribute(reinterpret_cast<const void*>(rnn_persistent),
                      hipFuncAttributeMaxDynamicSharedMemorySize, SMEM_BYTES);

  rnn_persistent<<<dim3(GB * GJ), dim3(256), SMEM_BYTES, stream>>>(
      x, Whx, Whh, bh, Wph, bp, out, hbuf);
}

// Round 17
// 991.456 us; speedup vs baseline: 1.0351x; 1.0351x over previous
//
#include <hip/hip_runtime.h>
#include <stdint.h>

// Persistent-kernel RNN: 256 wgs (1/CU), GB=32 x GJ=8, register-resident W,
// direct-global A bursts, MALL exchange with per-group flags (R15 = 968us best).
// R19 = R15 + two scheduling deltas (no protocol/volume change):
//  (a) PER-WAVE GATE, max-of-2: wave wv's k-range [wv*256,+256) = producer
//      slices 2wv and 2wv+1 ONLY. Lanes 0-1 poll those 2 flags; no gate
//      __syncthreads. Replaces the max-of-8 straggler wait with max-of-2 and
//      lets each wave burst as soon as ITS producers post. WAW unchanged: the
//      pre-store reduction barrier joins all 4 waves (= all 8 flags observed
//      collectively) before any hout store; TIED vmcnt(0) covers x loads.
//  (b) BG PHASE-STAGGER: the 32 bg chains are independent but launch
//      phase-locked -> their 8MB read bursts collide at the MALL every step.
//      One-time s_sleep ramp (~107ns x bg, max ~3.4us ~= one step) anti-aligns
//      the chains; contention itself makes the stagger self-sustaining.
// Evidence base: R18 rejected tag-polling (8KB data polls + retry storms beat
// 4B flag polls only if data is fresh on first try — it never is). R15==R16
// proved caching can't help (sc0sc1 stores write-invalidate the XCD L2).
// GJ=4 infeasible (512KB W/CU > 416KB reg+LDS ceiling) -> 8MB/step is the
// volume floor. Remaining costs: burst alignment + max-of-8 straggler — the
// two things this round attacks.
// Lessons kept: tied "+v" vmcnt waits + sched_barrier (R11 crash, R12 fix);
// sc0-only spin hangs (R3); buffer_inv sc1 = L2 nuke (R4); scope bits don't
// change exchange cost (R5==R6); data-polling retry storms (R9/R18).

#define BATCH 512
#define SEQ   256
#define HID   1024
#define CLS   128

#define GB 32          // batch groups
#define GJ 8           // hidden slices
#define BT 16          // batch rows per wg
#define JT 128         // hidden cols per wg
#define HSTR 132       // h exchange row stride (halves)
#define HS_OFF 16384   // halves: hS overlay at byte 32768 (above 32KB scratch)
#define SMEM_BYTES (32768 + BT * HSTR * 2)   // 36992 B
#define HBUF_HALVES (BATCH * HID)            // 1 MB per buffer

typedef __attribute__((ext_vector_type(8))) short  bf16x8;
typedef __attribute__((ext_vector_type(4))) short  s16x4;
typedef __attribute__((ext_vector_type(4))) float  f32x4;
typedef __attribute__((ext_vector_type(4))) int    i32x4;
typedef __attribute__((ext_vector_type(2))) unsigned int u32x2;

__device__ __forceinline__ unsigned short f2bf(float f) {
  unsigned int u = __float_as_uint(f);
  u = (u + 0x7FFFu + ((u >> 16) & 1u)) >> 16;   // RNE
  return (unsigned short)u;
}
__device__ __forceinline__ float b2f(short h) {
  return __uint_as_float(((unsigned int)(unsigned short)h) << 16);
}

// ---- device-coherent (MALL) protocol accesses ----
__device__ __forceinline__ void store_flag(int* p, int v) {
  asm volatile("global_store_dword %0, %1, off sc0 sc1" :: "v"(p), "v"(v) : "memory");
}
__device__ __forceinline__ int load_flag(const int* p) {
  int v;
  asm volatile("global_load_dword %0, %1, off sc0 sc1\n\t"
               "s_waitcnt vmcnt(0)" : "=v"(v) : "v"(p) : "memory");
  return v;
}
__device__ __forceinline__ void store16(void* p, i32x4 v) {
  asm volatile("global_store_dwordx4 %0, %1, off sc0 sc1" :: "v"(p), "v"(v) : "memory");
}
__device__ __forceinline__ void waitcnt0() {
  asm volatile("s_waitcnt vmcnt(0)" ::: "memory");
}
// raw workgroup barrier: drains LDS ops only
__device__ __forceinline__ void barrier_lgkm() {
  asm volatile("s_waitcnt lgkmcnt(0)\n\ts_barrier" ::: "memory");
}
// 4x dwordx4 coherent loads, 64B apart (MFMA k-step stride)
__device__ __forceinline__ void issue4_64(const void* p, i32x4& a, i32x4& b, i32x4& c, i32x4& d) {
  asm volatile(
    "global_load_dwordx4 %0, %4, off sc0 sc1\n\t"
    "global_load_dwordx4 %1, %4, off offset:64 sc0 sc1\n\t"
    "global_load_dwordx4 %2, %4, off offset:128 sc0 sc1\n\t"
    "global_load_dwordx4 %3, %4, off offset:192 sc0 sc1"
    : "=&v"(a), "=&v"(b), "=&v"(c), "=&v"(d)
    : "v"(p) : "memory");
}
// 4x dwordx4 coherent loads, 16B apart (contiguous 64 B — head staging)
__device__ __forceinline__ void issue4_16(const void* p, i32x4& a, i32x4& b, i32x4& c, i32x4& d) {
  asm volatile(
    "global_load_dwordx4 %0, %4, off sc0 sc1\n\t"
    "global_load_dwordx4 %1, %4, off offset:16 sc0 sc1\n\t"
    "global_load_dwordx4 %2, %4, off offset:32 sc0 sc1\n\t"
    "global_load_dwordx4 %3, %4, off offset:48 sc0 sc1"
    : "=&v"(a), "=&v"(b), "=&v"(c), "=&v"(d)
    : "v"(p) : "memory");
}
// register-TIED vmcnt(0): binds all 8 burst regs so no consumer can be
// scheduled above the wait (rule #18 / R11 crash lesson).
#define TIED_WAIT8(A0,A1,A2,A3,A4,A5,A6,A7) \
  asm volatile("s_waitcnt vmcnt(0)" \
               : "+v"(A0), "+v"(A1), "+v"(A2), "+v"(A3), \
                 "+v"(A4), "+v"(A5), "+v"(A6), "+v"(A7) :: "memory")

__device__ __forceinline__ void wr16(short* p, i32x4 v) {  // 16 B to LDS as 2x b64
  u32x2 lo, hi;
  lo.x = (unsigned)v.x; lo.y = (unsigned)v.y;
  hi.x = (unsigned)v.z; hi.y = (unsigned)v.w;
  *(u32x2*)p = lo;
  *(u32x2*)(p + 4) = hi;
}
__device__ __forceinline__ float tanh_fast(float z) {
  float e = __expf(2.f * z);
  return 1.f - 2.f / (e + 1.f);
}

#define MFMA(a, b, c) __builtin_amdgcn_mfma_f32_16x16x32_bf16((a), (b), (c), 0, 0, 0)

__global__ void __launch_bounds__(256, 1)
rnn_persistent(const float* __restrict__ x, const float* __restrict__ Whx,
               const float* __restrict__ Whh, const float* __restrict__ bh,
               const float* __restrict__ Wph, const float* __restrict__ bp,
               float* __restrict__ out, unsigned short* hbuf, int* flags)
{
  extern __shared__ short smem[];
  float* scr = (float*)smem;            // 32KB reduction scratch (head reuses)
  short* hS  = smem + HS_OFF;           // [BT][HSTR] exchange overlay

  const int tid  = threadIdx.x;
  const int bg   = blockIdx.x & 31;     // 32 batch groups
  const int jg   = blockIdx.x >> 5;     // 8 hidden slices
  const int lane = tid & 63;
  const int wv   = tid >> 6;            // wave = k-quarter owner
  const int l15  = lane & 15;
  const int quad = lane >> 4;

  // ---- W_hh into REGISTERS: cols jg*128+ct*16+l15, k = wv*256+ks*32+quad*8 ----
  bf16x8 barr[8][8];                    // 256 VGPR
#pragma unroll
  for (int ct = 0; ct < 8; ++ct) {
#pragma unroll
    for (int ks = 0; ks < 8; ++ks) {
      const float* wp = Whh + (jg * JT + ct * 16 + l15) * HID
                            + wv * 256 + ks * 32 + quad * 8;
      float4 fA = *(const float4*)(wp);
      float4 fB = *(const float4*)(wp + 4);
      union { bf16x8 v8; s16x4 h[2]; } u;
      u.h[0].x = (short)f2bf(fA.x); u.h[0].y = (short)f2bf(fA.y);
      u.h[0].z = (short)f2bf(fA.z); u.h[0].w = (short)f2bf(fA.w);
      u.h[1].x = (short)f2bf(fB.x); u.h[1].y = (short)f2bf(fB.y);
      u.h[1].z = (short)f2bf(fB.z); u.h[1].w = (short)f2bf(fB.w);
      barr[ct][ks] = u.v8;
    }
  }

  // this lane finishes col-tiles 2wv and 2wv+1 after the k-reduction
  const int j0 = jg * JT + wv * 32 + l15;
  const int j1 = j0 + 16;
  const float whx0 = Whx[j0], whx1 = Whx[j1];
  const float bhv0 = bh[j0],  bhv1 = bh[j1];

  // exchange thread mapping: 16 rows x 16 segs x 16 B
  const int sr  = tid >> 4;               // 0..15 row
  const int seg = tid & 15;               // 0..15

  int* myflags = flags + bg * 64;         // 8 flags, one 256B line per bg

  // ---- bg phase-stagger: anti-align the 32 independent chains (~107ns/bg,
  // max ~3.3us ~= one step period). MALL contention keeps them staggered.
  for (int i = 0; i < bg; ++i) asm volatile("s_sleep 4" ::: "memory");

  for (int t = 0; t < SEQ; ++t) {
    const unsigned short* hin = hbuf + ((t + 1) & 1) * HBUF_HALVES;
    unsigned short*      hout = hbuf + (t & 1) * HBUF_HALVES;

    f32x4 acc0 = {0,0,0,0}, acc1 = {0,0,0,0}, acc2 = {0,0,0,0}, acc3 = {0,0,0,0};
    f32x4 acc4 = {0,0,0,0}, acc5 = {0,0,0,0}, acc6 = {0,0,0,0}, acc7 = {0,0,0,0};

    // x for this step: rows bg*16 + quad*4 + rg (covered by TIED vmcnt(0))
    float xv[4];
    {
      const float* xp = x + (bg * BT + quad * 4) * SEQ + t;
#pragma unroll
      for (int rg = 0; rg < 4; ++rg) xv[rg] = xp[rg * SEQ];
    }

    if (t > 0) {
      // PER-WAVE gate (max-of-2): wave wv's k-range [wv*256,+256) comes from
      // producer slices jg' = 2wv, 2wv+1 only. Lanes 0-1 poll those flags;
      // lanes 2-63 are exec-masked -> whole wave gated (single PC). No
      // __syncthreads: the reduction barrier below joins all 4 waves
      // (collectively all 8 flags observed) BEFORE any hout store.
      if (lane < 2) {
        while (load_flag(myflags + wv * 2 + lane) < t) {
          asm volatile("s_sleep 1" ::: "memory");
        }
      }

      // A fragments direct from global in MFMA layout:
      // row l15 (BT=16: one row-tile), k-halves = wv*256 + quad*8 + ks*32.
      const short* pA = (const short*)hin + (bg * BT + l15) * HID
                        + wv * 256 + quad * 8;
      i32x4 A0, A1, A2, A3, A4, A5, A6, A7;
      issue4_64(pA,       A0, A1, A2, A3);   // ks 0..3
      issue4_64(pA + 128, A4, A5, A6, A7);   // ks 4..7 (+256 B)

      TIED_WAIT8(A0, A1, A2, A3, A4, A5, A6, A7);
      __builtin_amdgcn_sched_barrier(0);

#define KSTEP(Ar, KS) { \
      bf16x8 _a = *(const bf16x8*)&(Ar); \
      acc0 = MFMA(_a, barr[0][KS], acc0); acc1 = MFMA(_a, barr[1][KS], acc1); \
      acc2 = MFMA(_a, barr[2][KS], acc2); acc3 = MFMA(_a, barr[3][KS], acc3); \
      acc4 = MFMA(_a, barr[4][KS], acc4); acc5 = MFMA(_a, barr[5][KS], acc5); \
      acc6 = MFMA(_a, barr[6][KS], acc6); acc7 = MFMA(_a, barr[7][KS], acc7); }
      KSTEP(A0, 0) KSTEP(A1, 1) KSTEP(A2, 2) KSTEP(A3, 3)
      KSTEP(A4, 4) KSTEP(A5, 5) KSTEP(A6, 6) KSTEP(A7, 7)
#undef KSTEP
    }

    // ---- cross-wave k-reduction: scr[(ct*4 + wv)*64 + lane] (f32x4 slots) ----
    barrier_lgkm();   // JOIN: all 4 waves passed gates; prior readers done
#pragma unroll
    for (int ct = 0; ct < 8; ++ct) {
      f32x4 w = (ct == 0) ? acc0 : (ct == 1) ? acc1 : (ct == 2) ? acc2 :
                (ct == 3) ? acc3 : (ct == 4) ? acc4 : (ct == 5) ? acc5 :
                (ct == 6) ? acc6 : acc7;
      *(f32x4*)(scr + ((ct * 4 + wv) * 64 + lane) * 4) = w;
    }
    barrier_lgkm();
    {
      f32x4 f0 = {0,0,0,0}, f1 = {0,0,0,0};
#pragma unroll
      for (int w = 0; w < 4; ++w) {
        f0 += *(const f32x4*)(scr + (((2 * wv)     * 4 + w) * 64 + lane) * 4);
        f1 += *(const f32x4*)(scr + (((2 * wv + 1) * 4 + w) * 64 + lane) * 4);
      }
      // h = tanh(acc + x*whx + bh) -> hS (wave wv owns col-tiles 2wv, 2wv+1)
#pragma unroll
      for (int rg = 0; rg < 4; ++rg) {
        float z0 = f0[rg] + xv[rg] * whx0 + bhv0;
        hS[(quad * 4 + rg) * HSTR + wv * 32 + l15] = (short)f2bf(tanh_fast(z0));
        float z1 = f1[rg] + xv[rg] * whx1 + bhv1;
        hS[(quad * 4 + rg) * HSTR + wv * 32 + 16 + l15] = (short)f2bf(tanh_fast(z1));
      }
    }
    barrier_lgkm();   // hS complete
    {
      const short* hsrc = hS + sr * HSTR + seg * 8;
      u32x2 lo = *(const u32x2*)(hsrc);
      u32x2 hi = *(const u32x2*)(hsrc + 4);
      i32x4 sv; sv.x = (int)lo.x; sv.y = (int)lo.y; sv.z = (int)hi.x; sv.w = (int)hi.y;
      unsigned short* dst = hout + (bg * BT + sr) * HID + jg * JT + seg * 8;
      store16(dst, sv);
    }
    waitcnt0();          // this thread's coalesced store retired at MALL
    barrier_lgkm();      // all threads retired before the flag release
    if (tid == 0) store_flag(myflags + jg, t + 1);
  }

  // ---- output head: out[b, jg*16+cc] = h_last . W_ph[c] + b_p ----
  if (tid < GJ) {
    while (load_flag(myflags + tid) < SEQ) {
      asm volatile("s_sleep 1" ::: "memory");
    }
  }
  __syncthreads();

  // stage h_last (16 x 1024 bf16 = 32KB) into smem: thread (sr, seg) owns the
  // CONTIGUOUS 128 B at row sr, bytes seg*128..+128 (16B-stride loads).
  const unsigned short* hlast = hbuf + ((SEQ - 1) & 1) * HBUF_HALVES;
  {
    const char* lbase = (const char*)(hlast + (bg * BT + sr) * HID) + seg * 128;
    i32x4 p0, p1, p2, p3, p4, p5, p6, p7;
    issue4_16(lbase,      p0, p1, p2, p3);   // bytes 0,16,32,48
    issue4_16(lbase + 64, p4, p5, p6, p7);   // bytes 64,80,96,112
    waitcnt0();
    short* sdst = smem + sr * 1028 + seg * 64;   // [16][1028] halves
    wr16(sdst,      p0); wr16(sdst + 8,  p1); wr16(sdst + 16, p2); wr16(sdst + 24, p3);
    wr16(sdst + 32, p4); wr16(sdst + 40, p5); wr16(sdst + 48, p6); wr16(sdst + 56, p7);
  }
  __syncthreads();
  {
    const int hr = tid >> 4;            // 0..15 batch row
    const int cc = tid & 15;            // 0..15 class col within slice
    const int cg = jg * 16 + cc;
    const float* wp = Wph + cg * HID;
    const short* hs = smem + hr * 1028;
    float acc = 0.f;
#pragma unroll 8
    for (int k4 = 0; k4 < 256; ++k4) {
      float4 w  = *(const float4*)(wp + k4 * 4);
      s16x4 hv  = *(const s16x4*)(hs + k4 * 4);
      acc += b2f(hv.x) * w.x + b2f(hv.y) * w.y + b2f(hv.z) * w.z + b2f(hv.w) * w.w;
    }
    out[(bg * BT + hr) * CLS + cg] = acc + bp[cg];
  }
}

extern "C" void kernel_launch(void* const* d_in, const int* in_sizes, int n_in,
                              void* d_out, int out_size, void* d_ws, size_t ws_size,
                              hipStream_t stream) {
  const float* x   = (const float*)d_in[0];
  const float* Whx = (const float*)d_in[1];
  const float* Whh = (const float*)d_in[2];
  const float* bh  = (const float*)d_in[3];
  const float* Wph = (const float*)d_in[4];
  const float* bp  = (const float*)d_in[5];
  float* out = (float*)d_out;

  unsigned short* hbuf = (unsigned short*)d_ws;
  int* flags = (int*)((char*)d_ws + (size_t)2 * HBUF_HALVES * 2);

  // Zero flags each launch (stream-ordered, capture-safe): closes the
  // cross-launch race where stale flags (=SEQ) would let consumers run ahead.
  hipMemsetAsync(flags, 0, GB * 64 * sizeof(int), stream);

  hipFuncSetAttribute(reinterpret_cast<const void*>(rnn_persistent),
                      hipFuncAttributeMaxDynamicSharedMemorySize, SMEM_BYTES);

  rnn_persistent<<<dim3(GB * GJ), dim3(256), SMEM_BYTES, stream>>>(
      x, Whx, Whh, bh, Wph, bp, out, hbuf, flags);
}

// Round 18
// 963.818 us; speedup vs baseline: 1.0648x; 1.0287x over previous
//
#include <hip/hip_runtime.h>
#include <stdint.h>

// Persistent-kernel RNN: 256 wgs (1/CU), h exchanged via MALL (sc0 sc1) +
// per-group flags (R2 protocol).
// R20 = R15 VERBATIM RESUBMISSION — the session's best verified kernel
// (968.1 us; R16's L2-cached variant tied at 968.7; everything else 991-1230).
// Locking in the optimum as the final kernel.
//
// Why this is the structural floor (session evidence):
//  * Volume: GJ=8 is minimal — GJ=4 needs 1 KB/lane = 256 VGPR for W alone
//    (the whole file at 8 waves/CU); mixed reg+LDS needs 172KB LDS > 160KB.
//  * Caching: sc0sc1 stores write-INVALIDATE the XCD L2 (R15==R16, R7);
//    buffer_inv sc1 nukes the shared L2 (R4); no sub-device scope (R3).
//  * Protocol: flags beat sentinel (R5), sc1-only (R6), tags (R9/R18),
//    per-wave gates (R13/R19), phase-stagger (R19).
//  * Compute: register-resident W + direct-global A (0 LDS in MFMA path,
//    0 bank conflicts, 4 barriers/step) == staged-LDS timing (R12) — the
//    serialized MALL exchange chain is the step, not the compute.
// Structure: GB=32 x GJ=8; per wg: BT=16 batch rows x JT=128 hidden cols;
// W_hh in REGISTERS (barr[8][8] bf16x8 = 256 VGPR, wave = k-quarter);
// A (h) direct from global in MFMA fragment layout, 8-deep dwordx4 burst,
// register-TIED vmcnt wait + sched_barrier (R11 crash lesson); k-reduction
// via lane-contiguous f32x4 scratch (0 conflicts); R2 flag protocol with
// per-launch flag memset.

#define BATCH 512
#define SEQ   256
#define HID   1024
#define CLS   128

#define GB 32          // batch groups
#define GJ 8           // hidden slices (consumers per h byte — the lever)
#define BT 16          // batch rows per wg
#define JT 128         // hidden cols per wg
#define HSTR 132       // h exchange row stride (halves)
#define HS_OFF 16384   // halves: hS overlay at byte 32768 (above 32KB scratch)
#define SMEM_BYTES (32768 + BT * HSTR * 2)   // 36992 B
#define HBUF_HALVES (BATCH * HID)            // 1 MB per buffer

typedef __attribute__((ext_vector_type(8))) short  bf16x8;
typedef __attribute__((ext_vector_type(4))) short  s16x4;
typedef __attribute__((ext_vector_type(4))) float  f32x4;
typedef __attribute__((ext_vector_type(4))) int    i32x4;
typedef __attribute__((ext_vector_type(2))) unsigned int u32x2;

__device__ __forceinline__ unsigned short f2bf(float f) {
  unsigned int u = __float_as_uint(f);
  u = (u + 0x7FFFu + ((u >> 16) & 1u)) >> 16;   // RNE
  return (unsigned short)u;
}
__device__ __forceinline__ float b2f(short h) {
  return __uint_as_float(((unsigned int)(unsigned short)h) << 16);
}

// ---- device-coherent (MALL) protocol accesses ----
__device__ __forceinline__ void store_flag(int* p, int v) {
  asm volatile("global_store_dword %0, %1, off sc0 sc1" :: "v"(p), "v"(v) : "memory");
}
__device__ __forceinline__ int load_flag(const int* p) {
  int v;
  asm volatile("global_load_dword %0, %1, off sc0 sc1\n\t"
               "s_waitcnt vmcnt(0)" : "=v"(v) : "v"(p) : "memory");
  return v;
}
__device__ __forceinline__ void store16(void* p, i32x4 v) {
  asm volatile("global_store_dwordx4 %0, %1, off sc0 sc1" :: "v"(p), "v"(v) : "memory");
}
__device__ __forceinline__ void waitcnt0() {
  asm volatile("s_waitcnt vmcnt(0)" ::: "memory");
}
// raw workgroup barrier: drains LDS ops only
__device__ __forceinline__ void barrier_lgkm() {
  asm volatile("s_waitcnt lgkmcnt(0)\n\ts_barrier" ::: "memory");
}
// 4x dwordx4 coherent loads, 64B apart (MFMA k-step stride)
__device__ __forceinline__ void issue4_64(const void* p, i32x4& a, i32x4& b, i32x4& c, i32x4& d) {
  asm volatile(
    "global_load_dwordx4 %0, %4, off sc0 sc1\n\t"
    "global_load_dwordx4 %1, %4, off offset:64 sc0 sc1\n\t"
    "global_load_dwordx4 %2, %4, off offset:128 sc0 sc1\n\t"
    "global_load_dwordx4 %3, %4, off offset:192 sc0 sc1"
    : "=&v"(a), "=&v"(b), "=&v"(c), "=&v"(d)
    : "v"(p) : "memory");
}
// 4x dwordx4 coherent loads, 16B apart (CONTIGUOUS 64 B — head staging)
__device__ __forceinline__ void issue4_16(const void* p, i32x4& a, i32x4& b, i32x4& c, i32x4& d) {
  asm volatile(
    "global_load_dwordx4 %0, %4, off sc0 sc1\n\t"
    "global_load_dwordx4 %1, %4, off offset:16 sc0 sc1\n\t"
    "global_load_dwordx4 %2, %4, off offset:32 sc0 sc1\n\t"
    "global_load_dwordx4 %3, %4, off offset:48 sc0 sc1"
    : "=&v"(a), "=&v"(b), "=&v"(c), "=&v"(d)
    : "v"(p) : "memory");
}

__device__ __forceinline__ void wr16(short* p, i32x4 v) {  // 16 B to LDS as 2x b64
  u32x2 lo, hi;
  lo.x = (unsigned)v.x; lo.y = (unsigned)v.y;
  hi.x = (unsigned)v.z; hi.y = (unsigned)v.w;
  *(u32x2*)p = lo;
  *(u32x2*)(p + 4) = hi;
}
__device__ __forceinline__ float tanh_fast(float z) {
  float e = __expf(2.f * z);
  return 1.f - 2.f / (e + 1.f);
}

#define MFMA(a, b, c) __builtin_amdgcn_mfma_f32_16x16x32_bf16((a), (b), (c), 0, 0, 0)

__global__ void __launch_bounds__(256, 1)
rnn_persistent(const float* __restrict__ x, const float* __restrict__ Whx,
               const float* __restrict__ Whh, const float* __restrict__ bh,
               const float* __restrict__ Wph, const float* __restrict__ bp,
               float* __restrict__ out, unsigned short* hbuf, int* flags)
{
  extern __shared__ short smem[];
  float* scr = (float*)smem;            // 32KB reduction scratch (head reuses)
  short* hS  = smem + HS_OFF;           // [BT][HSTR] exchange overlay

  const int tid  = threadIdx.x;
  const int bg   = blockIdx.x & 31;     // 32 batch groups
  const int jg   = blockIdx.x >> 5;     // 8 hidden slices
  const int lane = tid & 63;
  const int wv   = tid >> 6;            // wave = k-quarter owner
  const int l15  = lane & 15;
  const int quad = lane >> 4;

  // ---- W_hh into REGISTERS: cols jg*128+ct*16+l15, k = wv*256+ks*32+quad*8 ----
  bf16x8 barr[8][8];                    // 256 VGPR
#pragma unroll
  for (int ct = 0; ct < 8; ++ct) {
#pragma unroll
    for (int ks = 0; ks < 8; ++ks) {
      const float* wp = Whh + (jg * JT + ct * 16 + l15) * HID
                            + wv * 256 + ks * 32 + quad * 8;
      float4 fA = *(const float4*)(wp);
      float4 fB = *(const float4*)(wp + 4);
      union { bf16x8 v8; s16x4 h[2]; } u;
      u.h[0].x = (short)f2bf(fA.x); u.h[0].y = (short)f2bf(fA.y);
      u.h[0].z = (short)f2bf(fA.z); u.h[0].w = (short)f2bf(fA.w);
      u.h[1].x = (short)f2bf(fB.x); u.h[1].y = (short)f2bf(fB.y);
      u.h[1].z = (short)f2bf(fB.z); u.h[1].w = (short)f2bf(fB.w);
      barr[ct][ks] = u.v8;
    }
  }

  // this lane finishes col-tiles 2wv and 2wv+1 after the k-reduction
  const int j0 = jg * JT + wv * 32 + l15;
  const int j1 = j0 + 16;
  const float whx0 = Whx[j0], whx1 = Whx[j1];
  const float bhv0 = bh[j0],  bhv1 = bh[j1];

  // exchange thread mapping: 16 rows x 16 segs x 16 B
  const int sr  = tid >> 4;               // 0..15 row
  const int seg = tid & 15;               // 0..15

  int* myflags = flags + bg * 64;         // 8 flags, one 256B line per bg

  for (int t = 0; t < SEQ; ++t) {
    const unsigned short* hin = hbuf + ((t + 1) & 1) * HBUF_HALVES;
    unsigned short*      hout = hbuf + (t & 1) * HBUF_HALVES;

    f32x4 acc0 = {0,0,0,0}, acc1 = {0,0,0,0}, acc2 = {0,0,0,0}, acc3 = {0,0,0,0};
    f32x4 acc4 = {0,0,0,0}, acc5 = {0,0,0,0}, acc6 = {0,0,0,0}, acc7 = {0,0,0,0};

    // x for this step: rows bg*16 + quad*4 + rg
    float xv[4];
    {
      const float* xp = x + (bg * BT + quad * 4) * SEQ + t;
#pragma unroll
      for (int rg = 0; rg < 4; ++rg) xv[rg] = xp[rg * SEQ];
    }

    if (t > 0) {
      // acquire (R2-verified): wait for all 8 peers of this batch-group
      if (tid < GJ) {
        while (load_flag(myflags + tid) < t) {
          asm volatile("s_sleep 1" ::: "memory");
        }
      }
      __syncthreads();   // full drain: clean vmcnt window for the burst

      // A fragments direct from global in MFMA layout:
      // row l15 (BT=16: one row-tile), k-halves = wv*256 + quad*8 + ks*32.
      const short* pA = (const short*)hin + (bg * BT + l15) * HID
                        + wv * 256 + quad * 8;
      i32x4 A0, A1, A2, A3, A4, A5, A6, A7;
      issue4_64(pA,       A0, A1, A2, A3);   // ks 0..3 (byte stride 64)
      issue4_64(pA + 128, A4, A5, A6, A7);   // ks 4..7 (pA+128 halves = +256 B)

      // TIED wait (rule #18): bind every A reg so MFMAs can't hoist above it.
      asm volatile("s_waitcnt vmcnt(0)"
                   : "+v"(A0), "+v"(A1), "+v"(A2), "+v"(A3),
                     "+v"(A4), "+v"(A5), "+v"(A6), "+v"(A7)
                   :: "memory");
      __builtin_amdgcn_sched_barrier(0);

#define KSTEP(Ar, KS) { \
      bf16x8 _a = *(const bf16x8*)&(Ar); \
      acc0 = MFMA(_a, barr[0][KS], acc0); acc1 = MFMA(_a, barr[1][KS], acc1); \
      acc2 = MFMA(_a, barr[2][KS], acc2); acc3 = MFMA(_a, barr[3][KS], acc3); \
      acc4 = MFMA(_a, barr[4][KS], acc4); acc5 = MFMA(_a, barr[5][KS], acc5); \
      acc6 = MFMA(_a, barr[6][KS], acc6); acc7 = MFMA(_a, barr[7][KS], acc7); }
      KSTEP(A0, 0) KSTEP(A1, 1) KSTEP(A2, 2) KSTEP(A3, 3)
      KSTEP(A4, 4) KSTEP(A5, 5) KSTEP(A6, 6) KSTEP(A7, 7)
#undef KSTEP
    }

    // ---- cross-wave k-reduction: scr[(ct*4 + wv)*64 + lane] (f32x4 slots) ----
    barrier_lgkm();   // prior-step scratch/hS readers done
#pragma unroll
    for (int ct = 0; ct < 8; ++ct) {
      f32x4 w = (ct == 0) ? acc0 : (ct == 1) ? acc1 : (ct == 2) ? acc2 :
                (ct == 3) ? acc3 : (ct == 4) ? acc4 : (ct == 5) ? acc5 :
                (ct == 6) ? acc6 : acc7;
      *(f32x4*)(scr + ((ct * 4 + wv) * 64 + lane) * 4) = w;
    }
    barrier_lgkm();
    {
      f32x4 f0 = {0,0,0,0}, f1 = {0,0,0,0};
#pragma unroll
      for (int w = 0; w < 4; ++w) {
        f0 += *(const f32x4*)(scr + (((2 * wv)     * 4 + w) * 64 + lane) * 4);
        f1 += *(const f32x4*)(scr + (((2 * wv + 1) * 4 + w) * 64 + lane) * 4);
      }
      // h = tanh(acc + x*whx + bh) -> hS (wave wv owns col-tiles 2wv, 2wv+1)
#pragma unroll
      for (int rg = 0; rg < 4; ++rg) {
        float z0 = f0[rg] + xv[rg] * whx0 + bhv0;
        hS[(quad * 4 + rg) * HSTR + wv * 32 + l15] = (short)f2bf(tanh_fast(z0));
        float z1 = f1[rg] + xv[rg] * whx1 + bhv1;
        hS[(quad * 4 + rg) * HSTR + wv * 32 + 16 + l15] = (short)f2bf(tanh_fast(z1));
      }
    }
    barrier_lgkm();   // hS complete
    {
      const short* hsrc = hS + sr * HSTR + seg * 8;
      u32x2 lo = *(const u32x2*)(hsrc);
      u32x2 hi = *(const u32x2*)(hsrc + 4);
      i32x4 sv; sv.x = (int)lo.x; sv.y = (int)lo.y; sv.z = (int)hi.x; sv.w = (int)hi.y;
      unsigned short* dst = hout + (bg * BT + sr) * HID + jg * JT + seg * 8;
      store16(dst, sv);
    }
    waitcnt0();          // this thread's coalesced store retired at MALL
    barrier_lgkm();      // all threads retired before the flag release
    if (tid == 0) store_flag(myflags + jg, t + 1);
  }

  // ---- output head: out[b, jg*16+cc] = h_last . W_ph[c] + b_p ----
  if (tid < GJ) {
    while (load_flag(myflags + tid) < SEQ) {
      asm volatile("s_sleep 1" ::: "memory");
    }
  }
  __syncthreads();

  // stage h_last (16 x 1024 bf16 = 32KB) into smem: thread (sr, seg) owns the
  // CONTIGUOUS 128 B at row sr, bytes seg*128..+128 (16B-stride loads).
  const unsigned short* hlast = hbuf + ((SEQ - 1) & 1) * HBUF_HALVES;
  {
    const char* lbase = (const char*)(hlast + (bg * BT + sr) * HID) + seg * 128;
    i32x4 p0, p1, p2, p3, p4, p5, p6, p7;
    issue4_16(lbase,      p0, p1, p2, p3);   // bytes 0,16,32,48
    issue4_16(lbase + 64, p4, p5, p6, p7);   // bytes 64,80,96,112
    waitcnt0();
    short* sdst = smem + sr * 1028 + seg * 64;   // [16][1028] halves
    wr16(sdst,      p0); wr16(sdst + 8,  p1); wr16(sdst + 16, p2); wr16(sdst + 24, p3);
    wr16(sdst + 32, p4); wr16(sdst + 40, p5); wr16(sdst + 48, p6); wr16(sdst + 56, p7);
  }
  __syncthreads();
  {
    const int hr = tid >> 4;            // 0..15 batch row
    const int cc = tid & 15;            // 0..15 class col within slice
    const int cg = jg * 16 + cc;
    const float* wp = Wph + cg * HID;
    const short* hs = smem + hr * 1028;
    float acc = 0.f;
#pragma unroll 8
    for (int k4 = 0; k4 < 256; ++k4) {
      float4 w  = *(const float4*)(wp + k4 * 4);
      s16x4 hv  = *(const s16x4*)(hs + k4 * 4);
      acc += b2f(hv.x) * w.x + b2f(hv.y) * w.y + b2f(hv.z) * w.z + b2f(hv.w) * w.w;
    }
    out[(bg * BT + hr) * CLS + cg] = acc + bp[cg];
  }
}

extern "C" void kernel_launch(void* const* d_in, const int* in_sizes, int n_in,
                              void* d_out, int out_size, void* d_ws, size_t ws_size,
                              hipStream_t stream) {
  const float* x   = (const float*)d_in[0];
  const float* Whx = (const float*)d_in[1];
  const float* Whh = (const float*)d_in[2];
  const float* bh  = (const float*)d_in[3];
  const float* Wph = (const float*)d_in[4];
  const float* bp  = (const float*)d_in[5];
  float* out = (float*)d_out;

  unsigned short* hbuf = (unsigned short*)d_ws;
  int* flags = (int*)((char*)d_ws + (size_t)2 * HBUF_HALVES * 2);

  // Zero flags each launch (stream-ordered, capture-safe): closes the
  // cross-launch race where stale flags (=SEQ) would let consumers run ahead.
  hipMemsetAsync(flags, 0, GB * 64 * sizeof(int), stream);

  hipFuncSetAttribute(reinterpret_cast<const void*>(rnn_persistent),
                      hipFuncAttributeMaxDynamicSharedMemorySize, SMEM_BYTES);

  rnn_persistent<<<dim3(GB * GJ), dim3(256), SMEM_BYTES, stream>>>(
      x, Whx, Whh, bh, Wph, bp, out, hbuf, flags);
}